// Round 17
// baseline (264.481 us; speedup 1.0000x reference)
//
#include <hip/hip_runtime.h>
#include <hip/hip_bf16.h>

// AlignmentContrastiveLoss on MI355X.
//   K1 normalize_pack: fp32 L2-normalize, drop CLS/special tokens, cast bf16.
//      A DENSE [256][36][1024]; B PADDED [256][32][1024]. 2 rows/wave.
//   K2 gemm_scores (R17): 288x256 tile -- 8 images (288 dense rows = 18
//      M-tiles) x 8 sentences, 512 threads = 8 waves as 2M x 4N; each wave
//      owns 9 M-tiles x 4 N-tiles (acc 144 regs, same per-wave shape as the
//      verified R14 kernel). Staged bytes per output drop 0.68x (A staged
//      once for 2x the output) and barrier-drain count halves; wave
//      residency unchanged (VGPR caps at 8 waves/CU either way).
//      Schedule/form/swizzle = R14 verbatim: BK=64 2-barrier single-buffer,
//      af[9]+bfr[4] batched ds_reads -> unbroken 36-MFMA cluster, 128-B
//      row-lines with phys_chunk = logical ^ (row&7) (measured ZERO
//      conflicts), inverse-swizzled global_load_lds source.
//      __launch_bounds__(512, 2) = 256-reg cap (",4" would cap at 128 and
//      spill the 144-reg acc -- the R4 trap).
//      Ledger of rejected variants: counted-vmcnt pipelines (R8 255, R15
//      233), dense-B (R9/R10), B-direct-to-VGPR (R13, +16% reg-staging tax),
//      XCD swizzle (R12, FETCH x3 on L3-fit).
//   K3 loss_fused: 64 blocks, block-partial reduction + one atomicAdd.

typedef __attribute__((ext_vector_type(8))) short bf16x8;
typedef __attribute__((ext_vector_type(4))) float f32x4;

#define NB   256
#define DIM  1024
#define LI   36     // valid image regions (dense pack stride)
#define LIP  36     // A pack stride (dense)
#define LS   30     // valid words per sentence
#define LSP  32     // B pack stride (padded to 2 x 16)

static __device__ inline ushort f2bf(float x) {
    union { __hip_bfloat16 h; ushort u; } cvt;
    cvt.h = __float2bfloat16(x);
    return cvt.u;
}

static __device__ __forceinline__ void gload_lds16(const void* g, void* l) {
    __builtin_amdgcn_global_load_lds(
        (const __attribute__((address_space(1))) void*)g,
        (__attribute__((address_space(3))) void*)l, 16, 0, 0);
}

// Two rows per wave (independent chains for ILP). Rows 0..9215 -> im'
// (dense); rows 9216..17407 -> s' ([256][32], word slots 30,31 zeroed).
__global__ __launch_bounds__(256) void normalize_pack(
    const float* __restrict__ im, const float* __restrict__ sq,
    short* __restrict__ imp, short* __restrict__ sp)
{
    const int gw   = (blockIdx.x * 256 + threadIdx.x) >> 6;   // wave id
    const int lane = threadIdx.x & 63;
    const int NIM  = NB * LI;   // 9216 dense image rows

    const float* src[2];
    short* dst[2];
    #pragma unroll
    for (int rr = 0; rr < 2; ++rr) {
        const int row = gw * 2 + rr;                 // 0..17407
        if (row < NIM) {
            int b = row / LI, i = row - b * LI;
            dst[rr] = imp + (size_t)row * DIM;
            src[rr] = im + ((size_t)b * 37 + i + 1) * DIM;   // drop CLS
        } else {
            int g2 = row - NIM;
            int b = g2 >> 5, j = g2 & 31;
            dst[rr] = sp + (size_t)g2 * DIM;
            src[rr] = (j < LS) ? (sq + ((size_t)b * 33 + j + 1) * DIM)
                               : nullptr;            // pad word slot
        }
    }

    float4 v[2][4];
    float ss[2] = {0.f, 0.f};
    #pragma unroll
    for (int rr = 0; rr < 2; ++rr) {
        if (src[rr]) {
            const float4* s4 = (const float4*)src[rr];
            #pragma unroll
            for (int t = 0; t < 4; ++t) {
                float4 x = s4[lane + 64 * t];
                v[rr][t] = x;
                ss[rr] += x.x * x.x + x.y * x.y + x.z * x.z + x.w * x.w;
            }
        }
    }
    // two interleaved (independent) shuffle-reduce chains
    #pragma unroll
    for (int o = 32; o >= 1; o >>= 1) {
        ss[0] += __shfl_xor(ss[0], o, 64);
        ss[1] += __shfl_xor(ss[1], o, 64);
    }
    #pragma unroll
    for (int rr = 0; rr < 2; ++rr) {
        if (src[rr]) {
            const float scale = 1.0f / fmaxf(sqrtf(ss[rr]), 1e-12f);
            ushort4* d4 = (ushort4*)dst[rr];
            #pragma unroll
            for (int t = 0; t < 4; ++t) {
                float4 x = v[rr][t];
                ushort4 o;
                o.x = f2bf(x.x * scale);
                o.y = f2bf(x.y * scale);
                o.z = f2bf(x.z * scale);
                o.w = f2bf(x.w * scale);
                d4[lane + 64 * t] = o;
            }
        } else {
            uint4 z = {0u, 0u, 0u, 0u};
            uint4* d4 = (uint4*)dst[rr];
            d4[lane] = z;
            d4[lane + 64] = z;
        }
    }
}

// Block: 512 threads = 8 waves (2M x 4N). blockIdx.x -> 8 images (288 dense
// rows), blockIdx.y -> 8 sentences (256 padded rows). Wave (wm, wn) owns
// M-half wm (9 M-tiles = images b0+4wm .. b0+4wm+3) x N-tiles 4wn..4wn+3
// (= sentences c0+2wn, c0+2wn+1) -> 8 score cells, wave-private.
//
// LDS: As[288][64], Bs[256][64] bf16 (68 KB); a row's BK=64 k-slice = one
// 128-B line = 8 chunks of 16 B. Swizzle: phys_chunk = logical ^ (row&7).
// Staging: one DMA instr = 1 KB = 8 rows; lane i -> row r0+(i>>3), phys
// chunk i&7; global source logical chunk (i&7)^(i>>3) [r0 % 8 == 0].
// 68 chunks/step (A 36, B 32); wave w takes cid = w + 8j (waves 0-3: 9,
// waves 4-7: 8). Reads: tile row bases are multiples of 16 (wm*144 incl.)
// -> row&7 = l15&7 -> phys chunk = (g*4+q) ^ (l15&7), per-lane constant.
// 8-consecutive-lane b128 groups cover all 32 banks once -> conflict-free.
__global__ __launch_bounds__(512, 2) void gemm_scores(
    const short* __restrict__ imp, const short* __restrict__ sp,
    const int* __restrict__ im_len, const int* __restrict__ s_len,
    float* __restrict__ scores)
{
    __shared__ short As[288 * 64];   // 36.9 KB
    __shared__ short Bs[256 * 64];   // 32.8 KB

    const int tid  = threadIdx.x;
    const int wave = tid >> 6;
    const int lane = tid & 63;
    const int q    = lane >> 4;
    const int l15  = lane & 15;
    const int wm   = wave >> 2;          // M-half (0,1)
    const int wn   = wave & 3;           // N-quarter (0..3)
    const int b0   = blockIdx.x * 8;
    const int c0   = blockIdx.y * 8;

    f32x4 acc[9][4];
    #pragma unroll
    for (int mt = 0; mt < 9; ++mt)
        #pragma unroll
        for (int t = 0; t < 4; ++t)
            acc[mt][t] = (f32x4){0.f, 0.f, 0.f, 0.f};

    // Per-lane staging source constants.
    const int srow   = lane >> 3;             // row within the 8-row chunk
    const int schunk = (lane & 7) ^ srow;     // inverse-swizzled 16B chunk
    const char* gA = (const char*)imp + (size_t)(b0 * LIP) * 2048
                     + srow * 2048 + schunk * 16;
    const char* gB = (const char*)sp + (size_t)(c0 * LSP) * 2048
                     + srow * 2048 + schunk * 16;

    // Read-side swizzled chunk byte offsets (per-lane constants).
    const int cs0 = ((q)     ^ (l15 & 7)) * 16;   // g = 0
    const int cs1 = ((4 + q) ^ (l15 & 7)) * 16;   // g = 1

    const int arow0 = wm * 144;   // this wave's A half base row

    for (int k0 = 0; k0 < DIM; k0 += 64) {
        const int kb = k0 * 2;   // byte offset of this K-slice within a row
        // stage 68 chunks (A 0..35, B 36..67), wave w -> cid = w + 8j
        #pragma unroll
        for (int j = 0; j < 9; ++j) {
            const int cid = wave + 8 * j;
            if (cid < 36) {
                gload_lds16(gA + cid * (8 * 2048) + kb, (char*)As + cid * 1024);
            } else if (cid < 68) {
                const int bc = cid - 36;
                gload_lds16(gB + bc * (8 * 2048) + kb, (char*)Bs + bc * 1024);
            }
        }
        __syncthreads();   // compiler emits vmcnt(0) drain for the DMA
        #pragma unroll
        for (int g = 0; g < 2; ++g) {
            const int cs = g ? cs1 : cs0;
            bf16x8 af[9], bfr[4];
            #pragma unroll
            for (int mt = 0; mt < 9; ++mt)
                af[mt] = *(const bf16x8*)((const char*)As + (arow0 + mt * 16 + l15) * 128 + cs);
            #pragma unroll
            for (int t = 0; t < 4; ++t)
                bfr[t] = *(const bf16x8*)((const char*)Bs + ((wn * 4 + t) * 16 + l15) * 128 + cs);
            #pragma unroll
            for (int mt = 0; mt < 9; ++mt)
                #pragma unroll
                for (int t = 0; t < 4; ++t)
                    acc[mt][t] = __builtin_amdgcn_mfma_f32_16x16x32_bf16(
                        af[mt], bfr[t], acc[mt][t], 0, 0, 0);
        }
        __syncthreads();
    }

    // ---- Fused epilogue (R14-verified; per-wave identical with b0w, wn) ----
    // C/D layout: lane holds col = l15, row = q*4 + r.
    // Half-local A row g = mt*16 + q*4 + r; image-in-half = (4*mt+q)/9,
    // region = g - 36*image. B col tile-aligned: sentence = c0 + wn*2 +
    // (t>>1), word jj = (t&1)*16 + l15.
    const int b0w = b0 + wm * 4;
    int il[4];
    #pragma unroll
    for (int bb = 0; bb < 4; ++bb) il[bb] = im_len[b0w + bb] - 1;   // [9, 36]

    float sc[4][2] = {{0.f,0.f},{0.f,0.f},{0.f,0.f},{0.f,0.f}};
    #pragma unroll
    for (int t = 0; t < 4; ++t) {
        const int c  = c0 + wn * 2 + (t >> 1);
        const int sl = s_len[c] - 3;                 // valid words, in [5, 30]
        const int jj = (t & 1) * 16 + l15;           // word index within sentence
        const bool jv = (jj < sl);

        float m[4] = {-3.4e38f, -3.4e38f, -3.4e38f, -3.4e38f};
        #pragma unroll
        for (int mt = 0; mt < 9; ++mt) {
            const int im_lo = (4 * mt) / 9;          // compile-time
            const int im_hi = (4 * mt + 3) / 9;      // compile-time
            const int thr   = 9 * im_hi - 4 * mt;    // q >= thr -> im_hi
            #pragma unroll
            for (int r = 0; r < 4; ++r) {
                const float v = acc[mt][t][r];
                const int base = mt * 16 + q * 4 + r;
                if (im_lo == im_hi) {
                    const int i = base - 36 * im_lo;
                    if (i < il[im_lo]) m[im_lo] = fmaxf(m[im_lo], v);
                } else {
                    const bool hi = (q >= thr);
                    if (!hi) {
                        const int i = base - 36 * im_lo;
                        if (i < il[im_lo]) m[im_lo] = fmaxf(m[im_lo], v);
                    } else {
                        const int i = base - 36 * im_hi;
                        if (i < il[im_hi]) m[im_hi] = fmaxf(m[im_hi], v);
                    }
                }
            }
        }
        #pragma unroll
        for (int bb = 0; bb < 4; ++bb) {
            float mm = m[bb];
            // combine the 4 row-quads -> full max over image bb's regions
            mm = fmaxf(mm, __shfl_xor(mm, 16, 64));
            mm = fmaxf(mm, __shfl_xor(mm, 32, 64));
            // masked (zeroed) entries participate in the max only when il < 36
            if (il[bb] < LI) mm = fmaxf(mm, 0.f);
            float v = (q == 0 && jv) ? mm : 0.f;     // count each column once
            #pragma unroll
            for (int off = 32; off >= 1; off >>= 1) v += __shfl_xor(v, off, 64);
            sc[bb][t >> 1] += v;
        }
    }
    if (lane == 0) {
        #pragma unroll
        for (int bb = 0; bb < 4; ++bb)
            #pragma unroll
            for (int h = 0; h < 2; ++h)
                scores[(b0w + bb) * NB + c0 + wn * 2 + h] = sc[bb][h];
    }
}

// Fused contrastive loss: 64 blocks x 4 waves; wave handles row/col t of the
// score matrix; block-level sum -> one atomicAdd into out[0].
__global__ __launch_bounds__(256) void loss_fused(
    const float* __restrict__ sc, float* __restrict__ out)
{
    const int wave = threadIdx.x >> 6, lane = threadIdx.x & 63;
    const int t = blockIdx.x * 4 + wave;
    const float dt = sc[t * (NB + 1)];
    float rowmax = 0.f, colmax = 0.f;
    #pragma unroll
    for (int p = 0; p < 4; ++p) {
        const int k = lane + 64 * p;
        const float r = sc[t * NB + k];
        const float c = sc[k * NB + t];
        if (k != t) {
            rowmax = fmaxf(rowmax, 0.2f + r - dt);
            colmax = fmaxf(colmax, 0.2f + c - dt);
        }
    }
    #pragma unroll
    for (int o = 32; o >= 1; o >>= 1) {
        rowmax = fmaxf(rowmax, __shfl_xor(rowmax, o, 64));
        colmax = fmaxf(colmax, __shfl_xor(colmax, o, 64));
    }
    __shared__ float red[4];
    if (lane == 0) red[wave] = fmaxf(rowmax, 0.f) + fmaxf(colmax, 0.f);
    __syncthreads();
    if (threadIdx.x == 0)
        atomicAdd(out, red[0] + red[1] + red[2] + red[3]);
}

extern "C" void kernel_launch(void* const* d_in, const int* in_sizes, int n_in,
                              void* d_out, int out_size, void* d_ws, size_t ws_size,
                              hipStream_t stream) {
    const float* im_set = (const float*)d_in[0];
    const float* s_seq  = (const float*)d_in[1];
    const int*   im_len = (const int*)d_in[2];
    const int*   s_len  = (const int*)d_in[3];
    float* out = (float*)d_out;

    char* ws = (char*)d_ws;
    const size_t imp_bytes = (size_t)NB * LIP * DIM * 2;   // 18.9 MB (dense)
    const size_t sp_bytes  = (size_t)NB * LSP * DIM * 2;   // 16.8 MB (padded)
    short* imp    = (short*)ws;
    short* sp     = (short*)(ws + imp_bytes);
    float* scores = (float*)(ws + imp_bytes + sp_bytes);   // 256 KB

    // 17408 rows, two per wave -> 8704 waves -> 2176 blocks
    normalize_pack<<<2176, 256, 0, stream>>>(im_set, s_seq, imp, sp);

    dim3 grid(NB / 8, NB / 8);   // 32 x 32 = 1024 blocks of 512 threads
    gemm_scores<<<grid, 512, 0, stream>>>(imp, sp, im_len, s_len, scores);

    loss_fused<<<64, 256, 0, stream>>>(scores, out);
}